// Round 1
// baseline (885.457 us; speedup 1.0000x reference)
//
#include <hip/hip_runtime.h>

// ---------------------------------------------------------------------------
// GCN forward: enc GEMM -> 3x (GEMM -> CSR aggregate +bias +relu) -> dec dot
// fp32 everywhere this round (correctness baseline; no fp32 MFMA on CDNA4).
// ---------------------------------------------------------------------------

#define HD 256   // hidden dim

__global__ void init_deg_kernel(int* __restrict__ deg, int n) {
  int i = blockIdx.x * blockDim.x + threadIdx.x;
  if (i < n) deg[i] = 1;   // self-loop
}

__global__ void count_deg_kernel(const int* __restrict__ dst, int* __restrict__ deg, int E) {
  int e = blockIdx.x * blockDim.x + threadIdx.x;
  if (e < E) atomicAdd(&deg[dst[e]], 1);
}

__global__ void dinv_kernel(const int* __restrict__ deg, float* __restrict__ dinv, int n) {
  int i = blockIdx.x * blockDim.x + threadIdx.x;
  if (i < n) dinv[i] = rsqrtf((float)deg[i]);
}

// Single-block Hillis-Steele scan over n counts -> exclusive row_ptr + cursor.
__global__ __launch_bounds__(1024) void scan_kernel(const int* __restrict__ cnt,
                                                    int* __restrict__ row_ptr,
                                                    int* __restrict__ cursor, int n) {
  __shared__ int sm[1024];
  __shared__ int carry_s;
  int tid = threadIdx.x;
  if (tid == 0) carry_s = 0;
  __syncthreads();
  for (int base = 0; base < n; base += 1024) {
    int i = base + tid;
    int v = (i < n) ? cnt[i] : 0;
    sm[tid] = v;
    __syncthreads();
    for (int off = 1; off < 1024; off <<= 1) {
      int t = (tid >= off) ? sm[tid - off] : 0;
      __syncthreads();
      sm[tid] += t;
      __syncthreads();
    }
    int incl = sm[tid];
    int carry = carry_s;
    int excl = carry + incl - v;
    if (i < n) { row_ptr[i] = excl; cursor[i] = excl; }
    __syncthreads();                 // everyone has read carry_s
    if (tid == 1023) carry_s = carry + sm[1023];
    __syncthreads();
  }
  if (tid == 0) row_ptr[n] = carry_s;
}

__global__ void fill_csr_kernel(const int* __restrict__ src, const int* __restrict__ dst,
                                const float* __restrict__ dinv, int* __restrict__ cursor,
                                int* __restrict__ col, float* __restrict__ wgt, int E) {
  int e = blockIdx.x * blockDim.x + threadIdx.x;
  if (e >= E) return;
  int s = src[e], d = dst[e];
  int pos = atomicAdd(&cursor[d], 1);
  col[pos] = s;
  wgt[pos] = dinv[s] * dinv[d];
}

__global__ void fill_self_kernel(const float* __restrict__ dinv, int* __restrict__ cursor,
                                 int* __restrict__ col, float* __restrict__ wgt, int n) {
  int i = blockIdx.x * blockDim.x + threadIdx.x;
  if (i >= n) return;
  int pos = atomicAdd(&cursor[i], 1);
  col[pos] = i;
  wgt[pos] = dinv[i] * dinv[i];
}

// ---------------------------------------------------------------------------
// fp32 tiled GEMM: C[M,Nn] = A[M,K] @ B[K,Nn] (+ bias). 64x64 tile, 4x4/thread.
// ---------------------------------------------------------------------------
#define BM 64
#define BN 64
#define BK 16

__global__ __launch_bounds__(256) void gemm_kernel(const float* __restrict__ A,
                                                   const float* __restrict__ B,
                                                   const float* __restrict__ bias,
                                                   float* __restrict__ C,
                                                   int M, int K, int Nn) {
  __shared__ float As[BK][BM + 4];
  __shared__ float Bs[BK][BN + 4];
  int nbx = Nn / BN;
  int bx = blockIdx.x % nbx;
  int by = blockIdx.x / nbx;
  int tid = threadIdx.x;
  int tx = tid & 15, ty = tid >> 4;
  int row0 = by * BM, col0 = bx * BN;

  int arow = tid >> 2;            // 0..63
  int acol = (tid & 3) * 4;       // 0,4,8,12
  int brow = tid >> 4;            // 0..15
  int bcol = (tid & 15) * 4;      // 0..60

  float c[4][4] = {};

  for (int k0 = 0; k0 < K; k0 += BK) {
    int gr = row0 + arow;
    float4 av = make_float4(0.f, 0.f, 0.f, 0.f);
    if (gr < M) av = *(const float4*)&A[(size_t)gr * K + k0 + acol];
    As[acol + 0][arow] = av.x;
    As[acol + 1][arow] = av.y;
    As[acol + 2][arow] = av.z;
    As[acol + 3][arow] = av.w;
    float4 bv = *(const float4*)&B[(size_t)(k0 + brow) * Nn + col0 + bcol];
    *(float4*)&Bs[brow][bcol] = bv;
    __syncthreads();
#pragma unroll
    for (int kk = 0; kk < BK; ++kk) {
      float a[4], b[4];
#pragma unroll
      for (int i = 0; i < 4; ++i) a[i] = As[kk][ty * 4 + i];
#pragma unroll
      for (int j = 0; j < 4; ++j) b[j] = Bs[kk][tx * 4 + j];
#pragma unroll
      for (int i = 0; i < 4; ++i)
#pragma unroll
        for (int j = 0; j < 4; ++j) c[i][j] += a[i] * b[j];
    }
    __syncthreads();
  }

  float4 bv = make_float4(0.f, 0.f, 0.f, 0.f);
  if (bias) bv = *(const float4*)&bias[col0 + tx * 4];
#pragma unroll
  for (int i = 0; i < 4; ++i) {
    int gr = row0 + ty * 4 + i;
    if (gr >= M) continue;
    float4 v = make_float4(c[i][0] + bv.x, c[i][1] + bv.y, c[i][2] + bv.z, c[i][3] + bv.w);
    *(float4*)&C[(size_t)gr * Nn + col0 + tx * 4] = v;
  }
}

// ---------------------------------------------------------------------------
// Aggregate: out[i,:] = relu( sum_j w_ij * tmp[col_j,:] + bias ).
// One wave per node; lane owns 4 features (float4). 4 nodes per 256-thr block.
// ---------------------------------------------------------------------------
__global__ __launch_bounds__(256) void aggregate_kernel(const float* __restrict__ tmp,
                                                        const int* __restrict__ row_ptr,
                                                        const int* __restrict__ col,
                                                        const float* __restrict__ wgt,
                                                        const float* __restrict__ bias,
                                                        float* __restrict__ out, int n) {
  int wave = threadIdx.x >> 6;
  int lane = threadIdx.x & 63;
  int node = blockIdx.x * 4 + wave;
  if (node >= n) return;
  const float4* tmp4 = (const float4*)tmp;
  float4 acc = ((const float4*)bias)[lane];
  int beg = row_ptr[node], end = row_ptr[node + 1];
  for (int p = beg; p < end; ++p) {
    int j = col[p];
    float w = wgt[p];
    float4 v = tmp4[(size_t)j * (HD / 4) + lane];
    acc.x += w * v.x;
    acc.y += w * v.y;
    acc.z += w * v.z;
    acc.w += w * v.w;
  }
  acc.x = fmaxf(acc.x, 0.f);
  acc.y = fmaxf(acc.y, 0.f);
  acc.z = fmaxf(acc.z, 0.f);
  acc.w = fmaxf(acc.w, 0.f);
  ((float4*)out)[(size_t)node * (HD / 4) + lane] = acc;
}

// out[node] = dot(h[node,:256], dec_W) + dec_b. One wave per node.
__global__ __launch_bounds__(256) void decoder_kernel(const float* __restrict__ h,
                                                      const float* __restrict__ dec_W,
                                                      const float* __restrict__ dec_b,
                                                      float* __restrict__ out, int n) {
  int wave = threadIdx.x >> 6;
  int lane = threadIdx.x & 63;
  int node = blockIdx.x * 4 + wave;
  if (node >= n) return;
  float4 a = ((const float4*)(h + (size_t)node * HD))[lane];
  float4 w = ((const float4*)dec_W)[lane];
  float s = a.x * w.x + a.y * w.y + a.z * w.z + a.w * w.w;
#pragma unroll
  for (int off = 32; off > 0; off >>= 1) s += __shfl_xor(s, off);
  if (lane == 0) out[node] = s + dec_b[0];
}

// ---------------------------------------------------------------------------

extern "C" void kernel_launch(void* const* d_in, const int* in_sizes, int n_in,
                              void* d_out, int out_size, void* d_ws, size_t ws_size,
                              hipStream_t stream) {
  const float* x      = (const float*)d_in[0];
  const int*   eidx   = (const int*)d_in[1];
  const float* enc_W  = (const float*)d_in[2];
  const float* enc_b  = (const float*)d_in[3];
  const float* W1     = (const float*)d_in[4];
  const float* b1     = (const float*)d_in[5];
  const float* W2     = (const float*)d_in[6];
  const float* b2     = (const float*)d_in[7];
  const float* W3     = (const float*)d_in[8];
  const float* b3     = (const float*)d_in[9];
  const float* dec_W  = (const float*)d_in[10];
  const float* dec_b  = (const float*)d_in[11];
  float* out = (float*)d_out;

  const int D_IN = 128;
  const int N = in_sizes[0] / D_IN;   // 50000
  const int E = in_sizes[1] / 2;      // 800000
  const int* src = eidx;
  const int* dst = eidx + E;

  // workspace layout
  float* hA      = (float*)d_ws;                    // N*HD
  float* hB      = hA + (size_t)N * HD;             // N*HD
  int*   deg     = (int*)(hB + (size_t)N * HD);     // N
  float* dinv    = (float*)(deg + N);               // N
  int*   row_ptr = (int*)(dinv + N);                // N+1
  int*   cursor  = row_ptr + (N + 1);               // N
  int*   col     = cursor + N;                      // E+N
  float* wgt     = (float*)(col + (E + N));         // E+N

  dim3 blk(256);
  dim3 gN((N + 255) / 256);
  dim3 gE((E + 255) / 256);

  // ---- build CSR (A_hat structure + norms) ----
  init_deg_kernel<<<gN, blk, 0, stream>>>(deg, N);
  count_deg_kernel<<<gE, blk, 0, stream>>>(dst, deg, E);
  dinv_kernel<<<gN, blk, 0, stream>>>(deg, dinv, N);
  scan_kernel<<<1, 1024, 0, stream>>>(deg, row_ptr, cursor, N);
  fill_csr_kernel<<<gE, blk, 0, stream>>>(src, dst, dinv, cursor, col, wgt, E);
  fill_self_kernel<<<gN, blk, 0, stream>>>(dinv, cursor, col, wgt, N);

  // ---- network ----
  int gy = (N + BM - 1) / BM;
  dim3 gemm_grid(gy * (HD / BN));
  dim3 agg_grid((N + 3) / 4);

  // encoder: hA = x @ enc_W + enc_b
  gemm_kernel<<<gemm_grid, blk, 0, stream>>>(x, enc_W, enc_b, hA, N, D_IN, HD);

  // conv1
  gemm_kernel<<<gemm_grid, blk, 0, stream>>>(hA, W1, nullptr, hB, N, HD, HD);
  aggregate_kernel<<<agg_grid, blk, 0, stream>>>(hB, row_ptr, col, wgt, b1, hA, N);
  // conv2
  gemm_kernel<<<gemm_grid, blk, 0, stream>>>(hA, W2, nullptr, hB, N, HD, HD);
  aggregate_kernel<<<agg_grid, blk, 0, stream>>>(hB, row_ptr, col, wgt, b2, hA, N);
  // conv3
  gemm_kernel<<<gemm_grid, blk, 0, stream>>>(hA, W3, nullptr, hB, N, HD, HD);
  aggregate_kernel<<<agg_grid, blk, 0, stream>>>(hB, row_ptr, col, wgt, b3, hA, N);

  // decoder
  decoder_kernel<<<agg_grid, blk, 0, stream>>>(hA, dec_W, dec_b, out, N);
}

// Round 2
// 717.060 us; speedup vs baseline: 1.2348x; 1.2348x over previous
//
#include <hip/hip_runtime.h>

// ---------------------------------------------------------------------------
// GCN forward, MFMA edition.
//   enc: split-bf16 MFMA GEMM (writes hi/lo bf16)
//   3x: split-bf16 MFMA GEMM (writes f32 tmp) -> CSR aggregate +bias+relu
//       (writes hi/lo bf16); conv3 aggregate fuses the decoder dot.
// Split-bf16: A=Ah+Al, B=Bh+Bl; C = Ah*Bh + Al*Bh + Ah*Bl (3 panels, fp32 acc)
// -> ~2^-18 relative error, i.e. fp32-equivalent for this test.
// ---------------------------------------------------------------------------

#define HD 256

typedef __attribute__((ext_vector_type(8))) short short8;
typedef __attribute__((ext_vector_type(4))) float f32x4;

__device__ __forceinline__ ushort bf16_rne(float x) {
  unsigned u = __float_as_uint(x);
  unsigned r = u + 0x7fffu + ((u >> 16) & 1u);
  return (ushort)(r >> 16);
}
__device__ __forceinline__ float bf16_to_f(ushort h) {
  return __uint_as_float(((unsigned)h) << 16);
}

// ---------------- CSR build ----------------
__global__ void init_deg_kernel(int* __restrict__ deg, int n) {
  int i = blockIdx.x * blockDim.x + threadIdx.x;
  if (i < n) deg[i] = 1;
}
__global__ void count_deg_kernel(const int* __restrict__ dst, int* __restrict__ deg, int E) {
  int e = blockIdx.x * blockDim.x + threadIdx.x;
  if (e < E) atomicAdd(&deg[dst[e]], 1);
}
__global__ void dinv_kernel(const int* __restrict__ deg, float* __restrict__ dinv, int n) {
  int i = blockIdx.x * blockDim.x + threadIdx.x;
  if (i < n) dinv[i] = rsqrtf((float)deg[i]);
}
__global__ __launch_bounds__(1024) void scan_kernel(const int* __restrict__ cnt,
                                                    int* __restrict__ row_ptr,
                                                    int* __restrict__ cursor, int n) {
  __shared__ int sm[1024];
  __shared__ int carry_s;
  int tid = threadIdx.x;
  if (tid == 0) carry_s = 0;
  __syncthreads();
  for (int base = 0; base < n; base += 1024) {
    int i = base + tid;
    int v = (i < n) ? cnt[i] : 0;
    sm[tid] = v;
    __syncthreads();
    for (int off = 1; off < 1024; off <<= 1) {
      int t = (tid >= off) ? sm[tid - off] : 0;
      __syncthreads();
      sm[tid] += t;
      __syncthreads();
    }
    int incl = sm[tid];
    int carry = carry_s;
    int excl = carry + incl - v;
    if (i < n) { row_ptr[i] = excl; cursor[i] = excl; }
    __syncthreads();
    if (tid == 1023) carry_s = carry + sm[1023];
    __syncthreads();
  }
  if (tid == 0) row_ptr[n] = carry_s;
}
__global__ void fill_csr_kernel(const int* __restrict__ src, const int* __restrict__ dst,
                                const float* __restrict__ dinv, int* __restrict__ cursor,
                                int* __restrict__ col, float* __restrict__ wgt, int E) {
  int e = blockIdx.x * blockDim.x + threadIdx.x;
  if (e >= E) return;
  int s = src[e], d = dst[e];
  int pos = atomicAdd(&cursor[d], 1);
  col[pos] = s;
  wgt[pos] = dinv[s] * dinv[d];
}
__global__ void fill_self_kernel(const float* __restrict__ dinv, int* __restrict__ cursor,
                                 int* __restrict__ col, float* __restrict__ wgt, int n) {
  int i = blockIdx.x * blockDim.x + threadIdx.x;
  if (i >= n) return;
  int pos = atomicAdd(&cursor[i], 1);
  col[pos] = i;
  wgt[pos] = dinv[i] * dinv[i];
}

// ---------------- hi/lo split preps ----------------
// x [M,128] f32 -> xhl [M,256] bf16 (hi cols 0..127, lo cols 128..255)
__global__ void split_x_kernel(const float* __restrict__ x, ushort* __restrict__ xhl, int total) {
  int idx = blockIdx.x * blockDim.x + threadIdx.x;
  if (idx >= total) return;
  int row = idx >> 7, c = idx & 127;
  float v = x[idx];
  ushort h = bf16_rne(v);
  ushort lo = bf16_rne(v - bf16_to_f(h));
  xhl[(size_t)row * 256 + c] = h;
  xhl[(size_t)row * 256 + 128 + c] = lo;
}
// W [K,256] f32 -> Bt [256, 2K] bf16 (transposed; hi cols 0..K-1, lo cols K..2K-1)
__global__ void split_w_kernel(const float* __restrict__ W, ushort* __restrict__ Bt, int K) {
  int idx = blockIdx.x * blockDim.x + threadIdx.x;
  if (idx >= K * 256) return;
  int k = idx >> 8, n = idx & 255;
  float v = W[idx];
  ushort h = bf16_rne(v);
  ushort lo = bf16_rne(v - bf16_to_f(h));
  Bt[(size_t)n * 2 * K + k] = h;
  Bt[(size_t)n * 2 * K + K + k] = lo;
}

// ---------------------------------------------------------------------------
// Split-bf16 MFMA GEMM. C[M,256] = (Ah+Al) @ (Bh+Bl), 3 panels of K.
// A: [M, ldA] bf16 bits, hi at cols [0,K), lo at [K,2K).
// Bt: [256, 2K] bf16 (B transposed), hi cols [0,K), lo cols [K,2K).
// Tile 128x128, 4 waves (2x2), each wave 64x64 = 4x4 frags of 16x16x32.
// BK=64; LDS tiles [128][64] bf16 with slot swizzle s^=(row&7), applied by
// pre-swizzling the global source (global_load_lds writes linearly).
// OUTMODE 0: f32 C [M,256].  OUTMODE 1: +bias, write hi/lo bf16 [M,512].
// ---------------------------------------------------------------------------
template<int OUTMODE>
__global__ __launch_bounds__(256) void mfma_gemm_kernel(
    const ushort* __restrict__ A, const ushort* __restrict__ Bt,
    const float* __restrict__ bias, void* __restrict__ outp,
    int M, int K, int ldA) {
  __shared__ __align__(16) ushort As[128 * 64];
  __shared__ __align__(16) ushort Bs[128 * 64];
  const int ldB = 2 * K;
  int row0 = (blockIdx.x >> 1) * 128;
  int col0 = (blockIdx.x & 1) * 128;
  int tid = threadIdx.x;
  int w = tid >> 6, l = tid & 63;
  int wm = w >> 1, wn = w & 1;

  f32x4 acc[4][4] = {};

  // staging constants: lane l stages 16B; chunk = 8 rows x 64 bf16
  int srow = l >> 3;                 // row within 8-row chunk
  int sslot = (l & 7) ^ srow;        // pre-swizzled source slot (16B units)
  // fragment constants
  int fr_a = wm * 64 + (l & 15);
  int fr_b = wn * 64 + (l & 15);
  int fgrp = l >> 4;                 // 0..3 (k-group)

  for (int p = 0; p < 3; ++p) {
    int aoff = (p == 1) ? K : 0;     // panels: Ah*Bh, Al*Bh, Ah*Bl
    int boff = (p == 2) ? K : 0;
    for (int kb = 0; kb < K; kb += 64) {
#pragma unroll
      for (int q = 0; q < 4; ++q) {
        int r = w * 32 + q * 8 + srow;
        int ga_row = row0 + r; if (ga_row >= M) ga_row = M - 1;
        const ushort* gA = A + (size_t)ga_row * ldA + aoff + kb + sslot * 8;
        __builtin_amdgcn_global_load_lds(
            (const __attribute__((address_space(1))) void*)gA,
            (__attribute__((address_space(3))) void*)&As[(w * 32 + q * 8) * 64],
            16, 0, 0);
        const ushort* gB = Bt + (size_t)(col0 + r) * ldB + boff + kb + sslot * 8;
        __builtin_amdgcn_global_load_lds(
            (const __attribute__((address_space(1))) void*)gB,
            (__attribute__((address_space(3))) void*)&Bs[(w * 32 + q * 8) * 64],
            16, 0, 0);
      }
      __syncthreads();
#pragma unroll
      for (int kk = 0; kk < 2; ++kk) {
        short8 av[4], bv[4];
#pragma unroll
        for (int i = 0; i < 4; ++i) {
          int ra = fr_a + i * 16;
          int sa = (kk * 4 + fgrp) ^ (ra & 7);
          av[i] = *(const short8*)&As[ra * 64 + sa * 8];
          int rb = fr_b + i * 16;
          int sb = (kk * 4 + fgrp) ^ (rb & 7);
          bv[i] = *(const short8*)&Bs[rb * 64 + sb * 8];
        }
#pragma unroll
        for (int mi = 0; mi < 4; ++mi)
#pragma unroll
          for (int ni = 0; ni < 4; ++ni)
            acc[mi][ni] = __builtin_amdgcn_mfma_f32_16x16x32_bf16(
                av[mi], bv[ni], acc[mi][ni], 0, 0, 0);
      }
      __syncthreads();
    }
  }

  // epilogue: D lane map: row=(l>>4)*4+reg, col=l&15
#pragma unroll
  for (int mi = 0; mi < 4; ++mi) {
#pragma unroll
    for (int r = 0; r < 4; ++r) {
      int grow = row0 + wm * 64 + mi * 16 + fgrp * 4 + r;
      if (grow >= M) continue;
#pragma unroll
      for (int ni = 0; ni < 4; ++ni) {
        int gcol = col0 + wn * 64 + ni * 16 + (l & 15);
        float v = acc[mi][ni][r];
        if (OUTMODE == 0) {
          ((float*)outp)[(size_t)grow * 256 + gcol] = v;
        } else {
          v += bias[gcol];
          ushort h = bf16_rne(v);
          ushort lo = bf16_rne(v - bf16_to_f(h));
          ushort* H = (ushort*)outp;
          H[(size_t)grow * 512 + gcol] = h;
          H[(size_t)grow * 512 + 256 + gcol] = lo;
        }
      }
    }
  }
}

// ---------------------------------------------------------------------------
// Aggregate: acc = bias + sum_j w_ij * tmp[col_j,:]; relu.
// DECODE=0: write hi/lo bf16 into hhl [n,512] (feeds next GEMM).
// DECODE=1: fused decoder: out[node] = dot(acc, decW) + decb.
// ---------------------------------------------------------------------------
template<bool DECODE>
__global__ __launch_bounds__(256) void aggregate_kernel(
    const float* __restrict__ tmp, const int* __restrict__ row_ptr,
    const int* __restrict__ col, const float* __restrict__ wgt,
    const float* __restrict__ bias, ushort* __restrict__ hhl,
    const float* __restrict__ decW, const float* __restrict__ decb,
    float* __restrict__ out, int n) {
  int wave = threadIdx.x >> 6;
  int lane = threadIdx.x & 63;
  int node = blockIdx.x * 4 + wave;
  if (node >= n) return;
  const float4* tmp4 = (const float4*)tmp;
  float4 acc = ((const float4*)bias)[lane];
  int beg = row_ptr[node], end = row_ptr[node + 1];
  for (int p = beg; p < end; ++p) {
    int j = col[p];
    float w = wgt[p];
    float4 v = tmp4[(size_t)j * (HD / 4) + lane];
    acc.x += w * v.x;
    acc.y += w * v.y;
    acc.z += w * v.z;
    acc.w += w * v.w;
  }
  acc.x = fmaxf(acc.x, 0.f);
  acc.y = fmaxf(acc.y, 0.f);
  acc.z = fmaxf(acc.z, 0.f);
  acc.w = fmaxf(acc.w, 0.f);
  if (!DECODE) {
    ushort4 h4, l4;
    float* a = (float*)&acc;
    ushort hh[4], ll[4];
#pragma unroll
    for (int i = 0; i < 4; ++i) {
      ushort h = bf16_rne(a[i]);
      hh[i] = h;
      ll[i] = bf16_rne(a[i] - bf16_to_f(h));
    }
    h4 = make_ushort4(hh[0], hh[1], hh[2], hh[3]);
    l4 = make_ushort4(ll[0], ll[1], ll[2], ll[3]);
    *(ushort4*)&hhl[(size_t)node * 512 + lane * 4] = h4;
    *(ushort4*)&hhl[(size_t)node * 512 + 256 + lane * 4] = l4;
  } else {
    float4 w = ((const float4*)decW)[lane];
    float s = acc.x * w.x + acc.y * w.y + acc.z * w.z + acc.w * w.w;
#pragma unroll
    for (int off = 32; off > 0; off >>= 1) s += __shfl_xor(s, off);
    if (lane == 0) out[node] = s + decb[0];
  }
}

// ---------------------------------------------------------------------------

extern "C" void kernel_launch(void* const* d_in, const int* in_sizes, int n_in,
                              void* d_out, int out_size, void* d_ws, size_t ws_size,
                              hipStream_t stream) {
  const float* x      = (const float*)d_in[0];
  const int*   eidx   = (const int*)d_in[1];
  const float* enc_W  = (const float*)d_in[2];
  const float* enc_b  = (const float*)d_in[3];
  const float* W1     = (const float*)d_in[4];
  const float* b1     = (const float*)d_in[5];
  const float* W2     = (const float*)d_in[6];
  const float* b2     = (const float*)d_in[7];
  const float* W3     = (const float*)d_in[8];
  const float* b3     = (const float*)d_in[9];
  const float* dec_W  = (const float*)d_in[10];
  const float* dec_b  = (const float*)d_in[11];
  float* out = (float*)d_out;

  const int D_IN = 128;
  const int N = in_sizes[0] / D_IN;   // 50000
  const int E = in_sizes[1] / 2;      // 800000
  const int* src = eidx;
  const int* dst = eidx + E;

  // workspace layout (ushort/f32 regions all 16B-aligned)
  float*  tmp = (float*)d_ws;                      // N*256 f32 (51.2MB)
  ushort* xhl = (ushort*)d_ws;                     // N*256 bf16 (overlays tmp;
                                                   // consumed before tmp written)
  ushort* hhl = (ushort*)(tmp + (size_t)N * 256);  // N*512 bf16 (51.2MB)
  ushort* BtE = hhl + (size_t)N * 512;             // 256*256
  ushort* Bt1 = BtE + 256 * 256;                   // 256*512
  ushort* Bt2 = Bt1 + 256 * 512;
  ushort* Bt3 = Bt2 + 256 * 512;
  int*   deg     = (int*)(Bt3 + 256 * 512);
  float* dinv    = (float*)(deg + N);
  int*   row_ptr = (int*)(dinv + N);
  int*   cursor  = row_ptr + (N + 1);
  int*   col     = cursor + N;
  float* wgt     = (float*)(col + (E + N));

  dim3 blk(256);
  dim3 gN((N + 255) / 256);
  dim3 gE((E + 255) / 256);

  // ---- CSR build ----
  init_deg_kernel<<<gN, blk, 0, stream>>>(deg, N);
  count_deg_kernel<<<gE, blk, 0, stream>>>(dst, deg, E);
  dinv_kernel<<<gN, blk, 0, stream>>>(deg, dinv, N);
  scan_kernel<<<1, 1024, 0, stream>>>(deg, row_ptr, cursor, N);
  fill_csr_kernel<<<gE, blk, 0, stream>>>(src, dst, dinv, cursor, col, wgt, E);
  fill_self_kernel<<<gN, blk, 0, stream>>>(dinv, cursor, col, wgt, N);

  // ---- hi/lo splits ----
  split_x_kernel<<<(N * D_IN + 255) / 256, blk, 0, stream>>>(x, xhl, N * D_IN);
  split_w_kernel<<<(128 * 256 + 255) / 256, blk, 0, stream>>>(enc_W, BtE, 128);
  split_w_kernel<<<(256 * 256 + 255) / 256, blk, 0, stream>>>(W1, Bt1, 256);
  split_w_kernel<<<(256 * 256 + 255) / 256, blk, 0, stream>>>(W2, Bt2, 256);
  split_w_kernel<<<(256 * 256 + 255) / 256, blk, 0, stream>>>(W3, Bt3, 256);

  // ---- network ----
  dim3 gemm_grid(((N + 127) / 128) * 2);
  dim3 agg_grid((N + 3) / 4);

  // encoder: hhl = split(x @ enc_W + enc_b)
  mfma_gemm_kernel<1><<<gemm_grid, blk, 0, stream>>>(xhl, BtE, enc_b, hhl, N, 128, 256);
  // conv1
  mfma_gemm_kernel<0><<<gemm_grid, blk, 0, stream>>>(hhl, Bt1, nullptr, tmp, N, 256, 512);
  aggregate_kernel<false><<<agg_grid, blk, 0, stream>>>(tmp, row_ptr, col, wgt, b1, hhl,
                                                        nullptr, nullptr, nullptr, N);
  // conv2
  mfma_gemm_kernel<0><<<gemm_grid, blk, 0, stream>>>(hhl, Bt2, nullptr, tmp, N, 256, 512);
  aggregate_kernel<false><<<agg_grid, blk, 0, stream>>>(tmp, row_ptr, col, wgt, b2, hhl,
                                                        nullptr, nullptr, nullptr, N);
  // conv3 + fused decoder
  mfma_gemm_kernel<0><<<gemm_grid, blk, 0, stream>>>(hhl, Bt3, nullptr, tmp, N, 256, 512);
  aggregate_kernel<true><<<agg_grid, blk, 0, stream>>>(tmp, row_ptr, col, wgt, b3, nullptr,
                                                       dec_W, dec_b, out, N);
}

// Round 4
// 662.689 us; speedup vs baseline: 1.3362x; 1.0820x over previous
//
#include <hip/hip_runtime.h>

// ---------------------------------------------------------------------------
// GCN forward, MFMA edition.
//   enc: split-bf16 MFMA GEMM (writes hi/lo bf16)
//   3x: split-bf16 MFMA GEMM (writes f32 tmp) -> CSR aggregate +bias+relu
//       (writes hi/lo bf16); conv3 aggregate fuses the decoder dot.
// Split-bf16: A=Ah+Al, B=Bh+Bl; C = Ah*Bh + Al*Bh + Ah*Bl (3 panels, fp32 acc)
// Round 3 (fixed): aggregate unrolled x8/x4 with 4 independent accumulators;
//          shuffle-based two-level scan. FMA4 macro -> inline fn (the macro
//          param `w` clobbered the `.w` member access).
// ---------------------------------------------------------------------------

#define HD 256

typedef __attribute__((ext_vector_type(8))) short short8;
typedef __attribute__((ext_vector_type(4))) float f32x4;

__device__ __forceinline__ ushort bf16_rne(float x) {
  unsigned u = __float_as_uint(x);
  unsigned r = u + 0x7fffu + ((u >> 16) & 1u);
  return (ushort)(r >> 16);
}
__device__ __forceinline__ float bf16_to_f(ushort h) {
  return __uint_as_float(((unsigned)h) << 16);
}

__device__ __forceinline__ void fma4(float4& acc, float s, const float4& v) {
  acc.x += s * v.x;
  acc.y += s * v.y;
  acc.z += s * v.z;
  acc.w += s * v.w;
}

// ---------------- CSR build ----------------
__global__ void init_deg_kernel(int* __restrict__ deg, int n) {
  int i = blockIdx.x * blockDim.x + threadIdx.x;
  if (i < n) deg[i] = 1;
}
__global__ void count_deg_kernel(const int* __restrict__ dst, int* __restrict__ deg, int E) {
  int e = blockIdx.x * blockDim.x + threadIdx.x;
  if (e < E) atomicAdd(&deg[dst[e]], 1);
}
__global__ void dinv_kernel(const int* __restrict__ deg, float* __restrict__ dinv, int n) {
  int i = blockIdx.x * blockDim.x + threadIdx.x;
  if (i < n) dinv[i] = rsqrtf((float)deg[i]);
}

// Two-level shuffle scan; 1024 threads = 16 waves.
__global__ __launch_bounds__(1024) void scan_kernel(const int* __restrict__ cnt,
                                                    int* __restrict__ row_ptr,
                                                    int* __restrict__ cursor, int n) {
  __shared__ int wsum[16];
  __shared__ int wpre[16];
  __shared__ int carry_s;
  int tid = threadIdx.x, lane = tid & 63, wid = tid >> 6;
  if (tid == 0) carry_s = 0;
  __syncthreads();
  for (int base = 0; base < n; base += 1024) {
    int i = base + tid;
    int v = (i < n) ? cnt[i] : 0;
    int s = v;
#pragma unroll
    for (int off = 1; off < 64; off <<= 1) {
      int t = __shfl_up(s, off, 64);
      if (lane >= off) s += t;
    }
    if (lane == 63) wsum[wid] = s;
    __syncthreads();
    if (wid == 0) {
      int ws = (lane < 16) ? wsum[lane] : 0;
      int ps = ws;
#pragma unroll
      for (int off = 1; off < 16; off <<= 1) {
        int t = __shfl_up(ps, off, 64);
        if (lane >= off) ps += t;
      }
      if (lane < 16) wpre[lane] = ps;  // inclusive over wave sums
    }
    __syncthreads();
    int carry = carry_s;
    int incl = s + (wid ? wpre[wid - 1] : 0);
    int excl = carry + incl - v;
    if (i < n) { row_ptr[i] = excl; cursor[i] = excl; }
    __syncthreads();
    if (tid == 1023) carry_s = carry + wpre[15];
    __syncthreads();
  }
  if (tid == 0) row_ptr[n] = carry_s;
}

__global__ void fill_csr_kernel(const int* __restrict__ src, const int* __restrict__ dst,
                                const float* __restrict__ dinv, int* __restrict__ cursor,
                                int* __restrict__ col, float* __restrict__ wgt, int E) {
  int e = blockIdx.x * blockDim.x + threadIdx.x;
  if (e >= E) return;
  int s = src[e], d = dst[e];
  int pos = atomicAdd(&cursor[d], 1);
  col[pos] = s;
  wgt[pos] = dinv[s] * dinv[d];
}
__global__ void fill_self_kernel(const float* __restrict__ dinv, int* __restrict__ cursor,
                                 int* __restrict__ col, float* __restrict__ wgt, int n) {
  int i = blockIdx.x * blockDim.x + threadIdx.x;
  if (i >= n) return;
  int pos = atomicAdd(&cursor[i], 1);
  col[pos] = i;
  wgt[pos] = dinv[i] * dinv[i];
}

// ---------------- hi/lo split preps ----------------
__global__ void split_x_kernel(const float* __restrict__ x, ushort* __restrict__ xhl, int total) {
  int idx = blockIdx.x * blockDim.x + threadIdx.x;
  if (idx >= total) return;
  int row = idx >> 7, c = idx & 127;
  float v = x[idx];
  ushort h = bf16_rne(v);
  ushort lo = bf16_rne(v - bf16_to_f(h));
  xhl[(size_t)row * 256 + c] = h;
  xhl[(size_t)row * 256 + 128 + c] = lo;
}
__global__ void split_w_kernel(const float* __restrict__ W, ushort* __restrict__ Bt, int K) {
  int idx = blockIdx.x * blockDim.x + threadIdx.x;
  if (idx >= K * 256) return;
  int k = idx >> 8, n = idx & 255;
  float v = W[idx];
  ushort h = bf16_rne(v);
  ushort lo = bf16_rne(v - bf16_to_f(h));
  Bt[(size_t)n * 2 * K + k] = h;
  Bt[(size_t)n * 2 * K + K + k] = lo;
}

// ---------------------------------------------------------------------------
// Split-bf16 MFMA GEMM (unchanged from round 2). Tile 128x128, 4 waves,
// BK=64, XOR-swizzled LDS via pre-swizzled global source.
// ---------------------------------------------------------------------------
template<int OUTMODE>
__global__ __launch_bounds__(256) void mfma_gemm_kernel(
    const ushort* __restrict__ A, const ushort* __restrict__ Bt,
    const float* __restrict__ bias, void* __restrict__ outp,
    int M, int K, int ldA) {
  __shared__ __align__(16) ushort As[128 * 64];
  __shared__ __align__(16) ushort Bs[128 * 64];
  const int ldB = 2 * K;
  int row0 = (blockIdx.x >> 1) * 128;
  int col0 = (blockIdx.x & 1) * 128;
  int tid = threadIdx.x;
  int w = tid >> 6, l = tid & 63;
  int wm = w >> 1, wn = w & 1;

  f32x4 acc[4][4] = {};

  int srow = l >> 3;
  int sslot = (l & 7) ^ srow;
  int fr_a = wm * 64 + (l & 15);
  int fr_b = wn * 64 + (l & 15);
  int fgrp = l >> 4;

  for (int p = 0; p < 3; ++p) {
    int aoff = (p == 1) ? K : 0;
    int boff = (p == 2) ? K : 0;
    for (int kb = 0; kb < K; kb += 64) {
#pragma unroll
      for (int q = 0; q < 4; ++q) {
        int r = w * 32 + q * 8 + srow;
        int ga_row = row0 + r; if (ga_row >= M) ga_row = M - 1;
        const ushort* gA = A + (size_t)ga_row * ldA + aoff + kb + sslot * 8;
        __builtin_amdgcn_global_load_lds(
            (const __attribute__((address_space(1))) void*)gA,
            (__attribute__((address_space(3))) void*)&As[(w * 32 + q * 8) * 64],
            16, 0, 0);
        const ushort* gB = Bt + (size_t)(col0 + r) * ldB + boff + kb + sslot * 8;
        __builtin_amdgcn_global_load_lds(
            (const __attribute__((address_space(1))) void*)gB,
            (__attribute__((address_space(3))) void*)&Bs[(w * 32 + q * 8) * 64],
            16, 0, 0);
      }
      __syncthreads();
#pragma unroll
      for (int kk = 0; kk < 2; ++kk) {
        short8 av[4], bv[4];
#pragma unroll
        for (int i = 0; i < 4; ++i) {
          int ra = fr_a + i * 16;
          int sa = (kk * 4 + fgrp) ^ (ra & 7);
          av[i] = *(const short8*)&As[ra * 64 + sa * 8];
          int rb = fr_b + i * 16;
          int sb = (kk * 4 + fgrp) ^ (rb & 7);
          bv[i] = *(const short8*)&Bs[rb * 64 + sb * 8];
        }
#pragma unroll
        for (int mi = 0; mi < 4; ++mi)
#pragma unroll
          for (int ni = 0; ni < 4; ++ni)
            acc[mi][ni] = __builtin_amdgcn_mfma_f32_16x16x32_bf16(
                av[mi], bv[ni], acc[mi][ni], 0, 0, 0);
      }
      __syncthreads();
    }
  }

#pragma unroll
  for (int mi = 0; mi < 4; ++mi) {
#pragma unroll
    for (int r = 0; r < 4; ++r) {
      int grow = row0 + wm * 64 + mi * 16 + fgrp * 4 + r;
      if (grow >= M) continue;
#pragma unroll
      for (int ni = 0; ni < 4; ++ni) {
        int gcol = col0 + wn * 64 + ni * 16 + (l & 15);
        float v = acc[mi][ni][r];
        if (OUTMODE == 0) {
          ((float*)outp)[(size_t)grow * 256 + gcol] = v;
        } else {
          v += bias[gcol];
          ushort h = bf16_rne(v);
          ushort lo = bf16_rne(v - bf16_to_f(h));
          ushort* H = (ushort*)outp;
          H[(size_t)grow * 512 + gcol] = h;
          H[(size_t)grow * 512 + 256 + gcol] = lo;
        }
      }
    }
  }
}

// ---------------------------------------------------------------------------
// Aggregate, unrolled x8/x4 with 4 independent accumulators for MLP.
// ---------------------------------------------------------------------------
template<bool DECODE>
__global__ __launch_bounds__(256) void aggregate_kernel(
    const float* __restrict__ tmp, const int* __restrict__ row_ptr,
    const int* __restrict__ col, const float* __restrict__ wgt,
    const float* __restrict__ bias, ushort* __restrict__ hhl,
    const float* __restrict__ decW, const float* __restrict__ decb,
    float* __restrict__ out, int n) {
  int wave = threadIdx.x >> 6;
  int lane = threadIdx.x & 63;
  int node = blockIdx.x * 4 + wave;
  if (node >= n) return;
  const float4* tmp4 = (const float4*)tmp;
  float4 a0 = ((const float4*)bias)[lane];
  float4 a1 = make_float4(0.f, 0.f, 0.f, 0.f);
  float4 a2 = make_float4(0.f, 0.f, 0.f, 0.f);
  float4 a3 = make_float4(0.f, 0.f, 0.f, 0.f);
  int p = row_ptr[node], end = row_ptr[node + 1];

  for (; p + 8 <= end; p += 8) {
    int j0 = col[p + 0], j1 = col[p + 1], j2 = col[p + 2], j3 = col[p + 3];
    int j4 = col[p + 4], j5 = col[p + 5], j6 = col[p + 6], j7 = col[p + 7];
    float w0 = wgt[p + 0], w1 = wgt[p + 1], w2 = wgt[p + 2], w3 = wgt[p + 3];
    float w4 = wgt[p + 4], w5 = wgt[p + 5], w6 = wgt[p + 6], w7 = wgt[p + 7];
    float4 v0 = tmp4[(size_t)j0 * 64 + lane];
    float4 v1 = tmp4[(size_t)j1 * 64 + lane];
    float4 v2 = tmp4[(size_t)j2 * 64 + lane];
    float4 v3 = tmp4[(size_t)j3 * 64 + lane];
    float4 v4 = tmp4[(size_t)j4 * 64 + lane];
    float4 v5 = tmp4[(size_t)j5 * 64 + lane];
    float4 v6 = tmp4[(size_t)j6 * 64 + lane];
    float4 v7 = tmp4[(size_t)j7 * 64 + lane];
    fma4(a0, w0, v0); fma4(a1, w1, v1); fma4(a2, w2, v2); fma4(a3, w3, v3);
    fma4(a0, w4, v4); fma4(a1, w5, v5); fma4(a2, w6, v6); fma4(a3, w7, v7);
  }
  for (; p + 4 <= end; p += 4) {
    int j0 = col[p + 0], j1 = col[p + 1], j2 = col[p + 2], j3 = col[p + 3];
    float w0 = wgt[p + 0], w1 = wgt[p + 1], w2 = wgt[p + 2], w3 = wgt[p + 3];
    float4 v0 = tmp4[(size_t)j0 * 64 + lane];
    float4 v1 = tmp4[(size_t)j1 * 64 + lane];
    float4 v2 = tmp4[(size_t)j2 * 64 + lane];
    float4 v3 = tmp4[(size_t)j3 * 64 + lane];
    fma4(a0, w0, v0); fma4(a1, w1, v1); fma4(a2, w2, v2); fma4(a3, w3, v3);
  }
  for (; p < end; ++p) {
    int j = col[p];
    float s = wgt[p];
    float4 v = tmp4[(size_t)j * 64 + lane];
    fma4(a0, s, v);
  }
  float4 acc;
  acc.x = fmaxf(a0.x + a1.x + a2.x + a3.x, 0.f);
  acc.y = fmaxf(a0.y + a1.y + a2.y + a3.y, 0.f);
  acc.z = fmaxf(a0.z + a1.z + a2.z + a3.z, 0.f);
  acc.w = fmaxf(a0.w + a1.w + a2.w + a3.w, 0.f);

  if (!DECODE) {
    float* a = (float*)&acc;
    ushort hh[4], ll[4];
#pragma unroll
    for (int i = 0; i < 4; ++i) {
      ushort h = bf16_rne(a[i]);
      hh[i] = h;
      ll[i] = bf16_rne(a[i] - bf16_to_f(h));
    }
    *(ushort4*)&hhl[(size_t)node * 512 + lane * 4] = make_ushort4(hh[0], hh[1], hh[2], hh[3]);
    *(ushort4*)&hhl[(size_t)node * 512 + 256 + lane * 4] = make_ushort4(ll[0], ll[1], ll[2], ll[3]);
  } else {
    float4 w = ((const float4*)decW)[lane];
    float s = acc.x * w.x + acc.y * w.y + acc.z * w.z + acc.w * w.w;
#pragma unroll
    for (int off = 32; off > 0; off >>= 1) s += __shfl_xor(s, off);
    if (lane == 0) out[node] = s + decb[0];
  }
}

// ---------------------------------------------------------------------------

extern "C" void kernel_launch(void* const* d_in, const int* in_sizes, int n_in,
                              void* d_out, int out_size, void* d_ws, size_t ws_size,
                              hipStream_t stream) {
  const float* x      = (const float*)d_in[0];
  const int*   eidx   = (const int*)d_in[1];
  const float* enc_W  = (const float*)d_in[2];
  const float* enc_b  = (const float*)d_in[3];
  const float* W1     = (const float*)d_in[4];
  const float* b1     = (const float*)d_in[5];
  const float* W2     = (const float*)d_in[6];
  const float* b2     = (const float*)d_in[7];
  const float* W3     = (const float*)d_in[8];
  const float* b3     = (const float*)d_in[9];
  const float* dec_W  = (const float*)d_in[10];
  const float* dec_b  = (const float*)d_in[11];
  float* out = (float*)d_out;

  const int D_IN = 128;
  const int N = in_sizes[0] / D_IN;   // 50000
  const int E = in_sizes[1] / 2;      // 800000
  const int* src = eidx;
  const int* dst = eidx + E;

  float*  tmp = (float*)d_ws;                      // N*256 f32
  ushort* xhl = (ushort*)d_ws;                     // overlays tmp (consumed first)
  ushort* hhl = (ushort*)(tmp + (size_t)N * 256);  // N*512 bf16
  ushort* BtE = hhl + (size_t)N * 512;
  ushort* Bt1 = BtE + 256 * 256;
  ushort* Bt2 = Bt1 + 256 * 512;
  ushort* Bt3 = Bt2 + 256 * 512;
  int*   deg     = (int*)(Bt3 + 256 * 512);
  float* dinv    = (float*)(deg + N);
  int*   row_ptr = (int*)(dinv + N);
  int*   cursor  = row_ptr + (N + 1);
  int*   col     = cursor + N;
  float* wgt     = (float*)(col + (E + N));

  dim3 blk(256);
  dim3 gN((N + 255) / 256);
  dim3 gE((E + 255) / 256);

  init_deg_kernel<<<gN, blk, 0, stream>>>(deg, N);
  count_deg_kernel<<<gE, blk, 0, stream>>>(dst, deg, E);
  dinv_kernel<<<gN, blk, 0, stream>>>(deg, dinv, N);
  scan_kernel<<<1, 1024, 0, stream>>>(deg, row_ptr, cursor, N);
  fill_csr_kernel<<<gE, blk, 0, stream>>>(src, dst, dinv, cursor, col, wgt, E);
  fill_self_kernel<<<gN, blk, 0, stream>>>(dinv, cursor, col, wgt, N);

  split_x_kernel<<<(N * D_IN + 255) / 256, blk, 0, stream>>>(x, xhl, N * D_IN);
  split_w_kernel<<<(128 * 256 + 255) / 256, blk, 0, stream>>>(enc_W, BtE, 128);
  split_w_kernel<<<(256 * 256 + 255) / 256, blk, 0, stream>>>(W1, Bt1, 256);
  split_w_kernel<<<(256 * 256 + 255) / 256, blk, 0, stream>>>(W2, Bt2, 256);
  split_w_kernel<<<(256 * 256 + 255) / 256, blk, 0, stream>>>(W3, Bt3, 256);

  dim3 gemm_grid(((N + 127) / 128) * 2);
  dim3 agg_grid((N + 3) / 4);

  mfma_gemm_kernel<1><<<gemm_grid, blk, 0, stream>>>(xhl, BtE, enc_b, hhl, N, 128, 256);
  mfma_gemm_kernel<0><<<gemm_grid, blk, 0, stream>>>(hhl, Bt1, nullptr, tmp, N, 256, 512);
  aggregate_kernel<false><<<agg_grid, blk, 0, stream>>>(tmp, row_ptr, col, wgt, b1, hhl,
                                                        nullptr, nullptr, nullptr, N);
  mfma_gemm_kernel<0><<<gemm_grid, blk, 0, stream>>>(hhl, Bt2, nullptr, tmp, N, 256, 512);
  aggregate_kernel<false><<<agg_grid, blk, 0, stream>>>(tmp, row_ptr, col, wgt, b2, hhl,
                                                        nullptr, nullptr, nullptr, N);
  mfma_gemm_kernel<0><<<gemm_grid, blk, 0, stream>>>(hhl, Bt3, nullptr, tmp, N, 256, 512);
  aggregate_kernel<true><<<agg_grid, blk, 0, stream>>>(tmp, row_ptr, col, wgt, b3, nullptr,
                                                       dec_W, dec_b, out, N);
}

// Round 5
// 478.791 us; speedup vs baseline: 1.8494x; 1.3841x over previous
//
#include <hip/hip_runtime.h>

// ---------------------------------------------------------------------------
// GCN forward, MFMA edition.
//   enc: split-bf16 MFMA GEMM (writes hi/lo bf16)
//   3x: split-bf16 MFMA GEMM (writes fp16 tmp) -> CSR aggregate +bias+relu
//       (writes hi/lo bf16); conv3 aggregate fuses the decoder dot.
// Split-bf16: A=Ah+Al, B=Bh+Bl; C = Ah*Bh + Al*Bh + Ah*Bl (3 panels, fp32 acc)
// Round 5: tmp stored as fp16 (2x less gather traffic; aggregate is
//          byte-bound on the L2-miss path per round-4 A/B: ILP unroll gave 0).
//          fp16 RNE rel err 2^-11 — ~4e-4 added error vs 3.73e-3 threshold.
// ---------------------------------------------------------------------------

#define HD 256

typedef __attribute__((ext_vector_type(8))) short short8;
typedef __attribute__((ext_vector_type(4))) float f32x4;
typedef __attribute__((ext_vector_type(4))) _Float16 half4;

__device__ __forceinline__ ushort bf16_rne(float x) {
  unsigned u = __float_as_uint(x);
  unsigned r = u + 0x7fffu + ((u >> 16) & 1u);
  return (ushort)(r >> 16);
}
__device__ __forceinline__ float bf16_to_f(ushort h) {
  return __uint_as_float(((unsigned)h) << 16);
}

__device__ __forceinline__ void fma4h(float4& acc, float s, const half4& v) {
  acc.x += s * (float)v.x;
  acc.y += s * (float)v.y;
  acc.z += s * (float)v.z;
  acc.w += s * (float)v.w;
}

// ---------------- CSR build ----------------
__global__ void init_deg_kernel(int* __restrict__ deg, int n) {
  int i = blockIdx.x * blockDim.x + threadIdx.x;
  if (i < n) deg[i] = 1;
}
__global__ void count_deg_kernel(const int* __restrict__ dst, int* __restrict__ deg, int E) {
  int e = blockIdx.x * blockDim.x + threadIdx.x;
  if (e < E) atomicAdd(&deg[dst[e]], 1);
}
__global__ void dinv_kernel(const int* __restrict__ deg, float* __restrict__ dinv, int n) {
  int i = blockIdx.x * blockDim.x + threadIdx.x;
  if (i < n) dinv[i] = rsqrtf((float)deg[i]);
}

// Two-level shuffle scan; 1024 threads = 16 waves.
__global__ __launch_bounds__(1024) void scan_kernel(const int* __restrict__ cnt,
                                                    int* __restrict__ row_ptr,
                                                    int* __restrict__ cursor, int n) {
  __shared__ int wsum[16];
  __shared__ int wpre[16];
  __shared__ int carry_s;
  int tid = threadIdx.x, lane = tid & 63, wid = tid >> 6;
  if (tid == 0) carry_s = 0;
  __syncthreads();
  for (int base = 0; base < n; base += 1024) {
    int i = base + tid;
    int v = (i < n) ? cnt[i] : 0;
    int s = v;
#pragma unroll
    for (int off = 1; off < 64; off <<= 1) {
      int t = __shfl_up(s, off, 64);
      if (lane >= off) s += t;
    }
    if (lane == 63) wsum[wid] = s;
    __syncthreads();
    if (wid == 0) {
      int ws = (lane < 16) ? wsum[lane] : 0;
      int ps = ws;
#pragma unroll
      for (int off = 1; off < 16; off <<= 1) {
        int t = __shfl_up(ps, off, 64);
        if (lane >= off) ps += t;
      }
      if (lane < 16) wpre[lane] = ps;  // inclusive over wave sums
    }
    __syncthreads();
    int carry = carry_s;
    int incl = s + (wid ? wpre[wid - 1] : 0);
    int excl = carry + incl - v;
    if (i < n) { row_ptr[i] = excl; cursor[i] = excl; }
    __syncthreads();
    if (tid == 1023) carry_s = carry + wpre[15];
    __syncthreads();
  }
  if (tid == 0) row_ptr[n] = carry_s;
}

__global__ void fill_csr_kernel(const int* __restrict__ src, const int* __restrict__ dst,
                                const float* __restrict__ dinv, int* __restrict__ cursor,
                                int* __restrict__ col, float* __restrict__ wgt, int E) {
  int e = blockIdx.x * blockDim.x + threadIdx.x;
  if (e >= E) return;
  int s = src[e], d = dst[e];
  int pos = atomicAdd(&cursor[d], 1);
  col[pos] = s;
  wgt[pos] = dinv[s] * dinv[d];
}
__global__ void fill_self_kernel(const float* __restrict__ dinv, int* __restrict__ cursor,
                                 int* __restrict__ col, float* __restrict__ wgt, int n) {
  int i = blockIdx.x * blockDim.x + threadIdx.x;
  if (i >= n) return;
  int pos = atomicAdd(&cursor[i], 1);
  col[pos] = i;
  wgt[pos] = dinv[i] * dinv[i];
}

// ---------------- hi/lo split preps ----------------
__global__ void split_x_kernel(const float* __restrict__ x, ushort* __restrict__ xhl, int total) {
  int idx = blockIdx.x * blockDim.x + threadIdx.x;
  if (idx >= total) return;
  int row = idx >> 7, c = idx & 127;
  float v = x[idx];
  ushort h = bf16_rne(v);
  ushort lo = bf16_rne(v - bf16_to_f(h));
  xhl[(size_t)row * 256 + c] = h;
  xhl[(size_t)row * 256 + 128 + c] = lo;
}
__global__ void split_w_kernel(const float* __restrict__ W, ushort* __restrict__ Bt, int K) {
  int idx = blockIdx.x * blockDim.x + threadIdx.x;
  if (idx >= K * 256) return;
  int k = idx >> 8, n = idx & 255;
  float v = W[idx];
  ushort h = bf16_rne(v);
  ushort lo = bf16_rne(v - bf16_to_f(h));
  Bt[(size_t)n * 2 * K + k] = h;
  Bt[(size_t)n * 2 * K + K + k] = lo;
}

// ---------------------------------------------------------------------------
// Split-bf16 MFMA GEMM. Tile 128x128, 4 waves, BK=64, XOR-swizzled LDS via
// pre-swizzled global source.
// OUTMODE 0: fp16 C [M,256].  OUTMODE 1: +bias, write hi/lo bf16 [M,512].
// ---------------------------------------------------------------------------
template<int OUTMODE>
__global__ __launch_bounds__(256) void mfma_gemm_kernel(
    const ushort* __restrict__ A, const ushort* __restrict__ Bt,
    const float* __restrict__ bias, void* __restrict__ outp,
    int M, int K, int ldA) {
  __shared__ __align__(16) ushort As[128 * 64];
  __shared__ __align__(16) ushort Bs[128 * 64];
  const int ldB = 2 * K;
  int row0 = (blockIdx.x >> 1) * 128;
  int col0 = (blockIdx.x & 1) * 128;
  int tid = threadIdx.x;
  int w = tid >> 6, l = tid & 63;
  int wm = w >> 1, wn = w & 1;

  f32x4 acc[4][4] = {};

  int srow = l >> 3;
  int sslot = (l & 7) ^ srow;
  int fr_a = wm * 64 + (l & 15);
  int fr_b = wn * 64 + (l & 15);
  int fgrp = l >> 4;

  for (int p = 0; p < 3; ++p) {
    int aoff = (p == 1) ? K : 0;
    int boff = (p == 2) ? K : 0;
    for (int kb = 0; kb < K; kb += 64) {
#pragma unroll
      for (int q = 0; q < 4; ++q) {
        int r = w * 32 + q * 8 + srow;
        int ga_row = row0 + r; if (ga_row >= M) ga_row = M - 1;
        const ushort* gA = A + (size_t)ga_row * ldA + aoff + kb + sslot * 8;
        __builtin_amdgcn_global_load_lds(
            (const __attribute__((address_space(1))) void*)gA,
            (__attribute__((address_space(3))) void*)&As[(w * 32 + q * 8) * 64],
            16, 0, 0);
        const ushort* gB = Bt + (size_t)(col0 + r) * ldB + boff + kb + sslot * 8;
        __builtin_amdgcn_global_load_lds(
            (const __attribute__((address_space(1))) void*)gB,
            (__attribute__((address_space(3))) void*)&Bs[(w * 32 + q * 8) * 64],
            16, 0, 0);
      }
      __syncthreads();
#pragma unroll
      for (int kk = 0; kk < 2; ++kk) {
        short8 av[4], bv[4];
#pragma unroll
        for (int i = 0; i < 4; ++i) {
          int ra = fr_a + i * 16;
          int sa = (kk * 4 + fgrp) ^ (ra & 7);
          av[i] = *(const short8*)&As[ra * 64 + sa * 8];
          int rb = fr_b + i * 16;
          int sb = (kk * 4 + fgrp) ^ (rb & 7);
          bv[i] = *(const short8*)&Bs[rb * 64 + sb * 8];
        }
#pragma unroll
        for (int mi = 0; mi < 4; ++mi)
#pragma unroll
          for (int ni = 0; ni < 4; ++ni)
            acc[mi][ni] = __builtin_amdgcn_mfma_f32_16x16x32_bf16(
                av[mi], bv[ni], acc[mi][ni], 0, 0, 0);
      }
      __syncthreads();
    }
  }

#pragma unroll
  for (int mi = 0; mi < 4; ++mi) {
#pragma unroll
    for (int r = 0; r < 4; ++r) {
      int grow = row0 + wm * 64 + mi * 16 + fgrp * 4 + r;
      if (grow >= M) continue;
#pragma unroll
      for (int ni = 0; ni < 4; ++ni) {
        int gcol = col0 + wn * 64 + ni * 16 + (l & 15);
        float v = acc[mi][ni][r];
        if (OUTMODE == 0) {
          ((_Float16*)outp)[(size_t)grow * 256 + gcol] = (_Float16)v;
        } else {
          v += bias[gcol];
          ushort h = bf16_rne(v);
          ushort lo = bf16_rne(v - bf16_to_f(h));
          ushort* H = (ushort*)outp;
          H[(size_t)grow * 512 + gcol] = h;
          H[(size_t)grow * 512 + 256 + gcol] = lo;
        }
      }
    }
  }
}

// ---------------------------------------------------------------------------
// Aggregate from fp16 tmp, unrolled x8/x4 with 4 independent accumulators.
// ---------------------------------------------------------------------------
template<bool DECODE>
__global__ __launch_bounds__(256) void aggregate_kernel(
    const _Float16* __restrict__ tmp, const int* __restrict__ row_ptr,
    const int* __restrict__ col, const float* __restrict__ wgt,
    const float* __restrict__ bias, ushort* __restrict__ hhl,
    const float* __restrict__ decW, const float* __restrict__ decb,
    float* __restrict__ out, int n) {
  int wave = threadIdx.x >> 6;
  int lane = threadIdx.x & 63;
  int node = blockIdx.x * 4 + wave;
  if (node >= n) return;
  const half4* tmp4 = (const half4*)tmp;   // 64 half4 per 256-wide row
  float4 a0 = ((const float4*)bias)[lane];
  float4 a1 = make_float4(0.f, 0.f, 0.f, 0.f);
  float4 a2 = make_float4(0.f, 0.f, 0.f, 0.f);
  float4 a3 = make_float4(0.f, 0.f, 0.f, 0.f);
  int p = row_ptr[node], end = row_ptr[node + 1];

  for (; p + 8 <= end; p += 8) {
    int j0 = col[p + 0], j1 = col[p + 1], j2 = col[p + 2], j3 = col[p + 3];
    int j4 = col[p + 4], j5 = col[p + 5], j6 = col[p + 6], j7 = col[p + 7];
    float w0 = wgt[p + 0], w1 = wgt[p + 1], w2 = wgt[p + 2], w3 = wgt[p + 3];
    float w4 = wgt[p + 4], w5 = wgt[p + 5], w6 = wgt[p + 6], w7 = wgt[p + 7];
    half4 v0 = tmp4[(size_t)j0 * 64 + lane];
    half4 v1 = tmp4[(size_t)j1 * 64 + lane];
    half4 v2 = tmp4[(size_t)j2 * 64 + lane];
    half4 v3 = tmp4[(size_t)j3 * 64 + lane];
    half4 v4 = tmp4[(size_t)j4 * 64 + lane];
    half4 v5 = tmp4[(size_t)j5 * 64 + lane];
    half4 v6 = tmp4[(size_t)j6 * 64 + lane];
    half4 v7 = tmp4[(size_t)j7 * 64 + lane];
    fma4h(a0, w0, v0); fma4h(a1, w1, v1); fma4h(a2, w2, v2); fma4h(a3, w3, v3);
    fma4h(a0, w4, v4); fma4h(a1, w5, v5); fma4h(a2, w6, v6); fma4h(a3, w7, v7);
  }
  for (; p + 4 <= end; p += 4) {
    int j0 = col[p + 0], j1 = col[p + 1], j2 = col[p + 2], j3 = col[p + 3];
    float w0 = wgt[p + 0], w1 = wgt[p + 1], w2 = wgt[p + 2], w3 = wgt[p + 3];
    half4 v0 = tmp4[(size_t)j0 * 64 + lane];
    half4 v1 = tmp4[(size_t)j1 * 64 + lane];
    half4 v2 = tmp4[(size_t)j2 * 64 + lane];
    half4 v3 = tmp4[(size_t)j3 * 64 + lane];
    fma4h(a0, w0, v0); fma4h(a1, w1, v1); fma4h(a2, w2, v2); fma4h(a3, w3, v3);
  }
  for (; p < end; ++p) {
    int j = col[p];
    float s = wgt[p];
    half4 v = tmp4[(size_t)j * 64 + lane];
    fma4h(a0, s, v);
  }
  float4 acc;
  acc.x = fmaxf(a0.x + a1.x + a2.x + a3.x, 0.f);
  acc.y = fmaxf(a0.y + a1.y + a2.y + a3.y, 0.f);
  acc.z = fmaxf(a0.z + a1.z + a2.z + a3.z, 0.f);
  acc.w = fmaxf(a0.w + a1.w + a2.w + a3.w, 0.f);

  if (!DECODE) {
    float* a = (float*)&acc;
    ushort hh[4], ll[4];
#pragma unroll
    for (int i = 0; i < 4; ++i) {
      ushort h = bf16_rne(a[i]);
      hh[i] = h;
      ll[i] = bf16_rne(a[i] - bf16_to_f(h));
    }
    *(ushort4*)&hhl[(size_t)node * 512 + lane * 4] = make_ushort4(hh[0], hh[1], hh[2], hh[3]);
    *(ushort4*)&hhl[(size_t)node * 512 + 256 + lane * 4] = make_ushort4(ll[0], ll[1], ll[2], ll[3]);
  } else {
    float4 w = ((const float4*)decW)[lane];
    float s = acc.x * w.x + acc.y * w.y + acc.z * w.z + acc.w * w.w;
#pragma unroll
    for (int off = 32; off > 0; off >>= 1) s += __shfl_xor(s, off);
    if (lane == 0) out[node] = s + decb[0];
  }
}

// ---------------------------------------------------------------------------

extern "C" void kernel_launch(void* const* d_in, const int* in_sizes, int n_in,
                              void* d_out, int out_size, void* d_ws, size_t ws_size,
                              hipStream_t stream) {
  const float* x      = (const float*)d_in[0];
  const int*   eidx   = (const int*)d_in[1];
  const float* enc_W  = (const float*)d_in[2];
  const float* enc_b  = (const float*)d_in[3];
  const float* W1     = (const float*)d_in[4];
  const float* b1     = (const float*)d_in[5];
  const float* W2     = (const float*)d_in[6];
  const float* b2     = (const float*)d_in[7];
  const float* W3     = (const float*)d_in[8];
  const float* b3     = (const float*)d_in[9];
  const float* dec_W  = (const float*)d_in[10];
  const float* dec_b  = (const float*)d_in[11];
  float* out = (float*)d_out;

  const int D_IN = 128;
  const int N = in_sizes[0] / D_IN;   // 50000
  const int E = in_sizes[1] / 2;      // 800000
  const int* src = eidx;
  const int* dst = eidx + E;

  // workspace layout: keep region sizes from round 4 (tmp region sized for
  // f32 but now holds fp16 + the xhl overlay; xhl consumed before tmp write)
  float*     tmpRegion = (float*)d_ws;                 // N*256 f32-sized region
  _Float16*  tmp = (_Float16*)d_ws;                    // N*256 fp16 (first half)
  ushort*    xhl = (ushort*)((char*)d_ws + (size_t)N * 256 * 2);  // N*256 bf16
  ushort* hhl = (ushort*)(tmpRegion + (size_t)N * 256);  // N*512 bf16
  ushort* BtE = hhl + (size_t)N * 512;
  ushort* Bt1 = BtE + 256 * 256;
  ushort* Bt2 = Bt1 + 256 * 512;
  ushort* Bt3 = Bt2 + 256 * 512;
  int*   deg     = (int*)(Bt3 + 256 * 512);
  float* dinv    = (float*)(deg + N);
  int*   row_ptr = (int*)(dinv + N);
  int*   cursor  = row_ptr + (N + 1);
  int*   col     = cursor + N;
  float* wgt     = (float*)(col + (E + N));

  dim3 blk(256);
  dim3 gN((N + 255) / 256);
  dim3 gE((E + 255) / 256);

  init_deg_kernel<<<gN, blk, 0, stream>>>(deg, N);
  count_deg_kernel<<<gE, blk, 0, stream>>>(dst, deg, E);
  dinv_kernel<<<gN, blk, 0, stream>>>(deg, dinv, N);
  scan_kernel<<<1, 1024, 0, stream>>>(deg, row_ptr, cursor, N);
  fill_csr_kernel<<<gE, blk, 0, stream>>>(src, dst, dinv, cursor, col, wgt, E);
  fill_self_kernel<<<gN, blk, 0, stream>>>(dinv, cursor, col, wgt, N);

  split_x_kernel<<<(N * D_IN + 255) / 256, blk, 0, stream>>>(x, xhl, N * D_IN);
  split_w_kernel<<<(128 * 256 + 255) / 256, blk, 0, stream>>>(enc_W, BtE, 128);
  split_w_kernel<<<(256 * 256 + 255) / 256, blk, 0, stream>>>(W1, Bt1, 256);
  split_w_kernel<<<(256 * 256 + 255) / 256, blk, 0, stream>>>(W2, Bt2, 256);
  split_w_kernel<<<(256 * 256 + 255) / 256, blk, 0, stream>>>(W3, Bt3, 256);

  dim3 gemm_grid(((N + 127) / 128) * 2);
  dim3 agg_grid((N + 3) / 4);

  mfma_gemm_kernel<1><<<gemm_grid, blk, 0, stream>>>(xhl, BtE, enc_b, hhl, N, 128, 256);
  mfma_gemm_kernel<0><<<gemm_grid, blk, 0, stream>>>(hhl, Bt1, nullptr, tmp, N, 256, 512);
  aggregate_kernel<false><<<agg_grid, blk, 0, stream>>>(tmp, row_ptr, col, wgt, b1, hhl,
                                                        nullptr, nullptr, nullptr, N);
  mfma_gemm_kernel<0><<<gemm_grid, blk, 0, stream>>>(hhl, Bt2, nullptr, tmp, N, 256, 512);
  aggregate_kernel<false><<<agg_grid, blk, 0, stream>>>(tmp, row_ptr, col, wgt, b2, hhl,
                                                        nullptr, nullptr, nullptr, N);
  mfma_gemm_kernel<0><<<gemm_grid, blk, 0, stream>>>(hhl, Bt3, nullptr, tmp, N, 256, 512);
  aggregate_kernel<true><<<agg_grid, blk, 0, stream>>>(tmp, row_ptr, col, wgt, b3, nullptr,
                                                       dec_W, dec_b, out, N);
}